// Round 3
// baseline (97.746 us; speedup 1.0000x reference)
//
#include <hip/hip_runtime.h>

typedef __attribute__((ext_vector_type(4))) float f32x4;

#define D_ 64
#define K_ 512
#define QB 256          // queries per block
#define KB 256          // codebook entries per chunk
#define NCHUNK (K_ / KB)
#define MT 8            // queries per thread
#define NT 16           // entries per thread
#define NTHREADS 512

__device__ __forceinline__ void gload_lds16(const float* g, float* lds) {
  __builtin_amdgcn_global_load_lds(
      (const __attribute__((address_space(1))) void*)g,
      (__attribute__((address_space(3))) void*)lds, 16, 0, 0);
}

__global__ __launch_bounds__(NTHREADS, 2)
void vq_assign_gather(const float* __restrict__ codes,
                      const float* __restrict__ codebook,
                      float* __restrict__ out) {
  // A: [q][16B-group], groups XOR-swizzled by (q>>3)&7  -> 64 KB
  __shared__ float A[QB * D_];
  // Bt: [d][j][tx][4] grouped transpose: entry e=tx*16+4j+i at d*256+j*64+tx*4+i -> 64 KB
  __shared__ float Bt[D_ * KB];
  __shared__ float esq_s[KB];
  __shared__ int best_s[QB];

  const int t = threadIdx.x;
  const int tx = t & 15;           // entry-group: 16 groups x 16 entries
  const int ty = t >> 4;           // query-group: 32 groups x 8 queries
  const int lane = t & 63;
  const int wv = t >> 6;           // wave 0..7
  const long long qbase = (long long)blockIdx.x * QB;

  // ---- stage codes tile (64 KB) via async global->LDS, pre-swizzled source ----
  {
    const float* srcb = codes + qbase * D_;
#pragma unroll
    for (int r = 0; r < 8; ++r) {
      const int sw = (4 * r + (wv >> 1)) & 7;                 // wave-uniform
      const float* src = srcb + (r * 32 + wv * 4 + (lane >> 4)) * 64
                              + (((lane & 15) ^ sw) << 2);     // per-lane
      gload_lds16(src, A + r * 2048 + wv * 256);               // wave-uniform dest
    }
  }

  // ---- codebook chunk staging (reg-staged, grouped-transposed into LDS) ----
  const int se = t >> 1;            // entry 0..255 within chunk
  const int sdh = (t & 1) * 32;     // d-half 0 or 32
  const int wtx = se >> 4;          // entry's tx group
  const int wj = (se & 15) >> 2;    // entry's j group
  const int wi = se & 3;            // entry's i
  f32x4 pre[8];

  auto load_chunk = [&](int c) {
    const float* g = codebook + (c * KB + se) * D_ + sdh;
#pragma unroll
    for (int i = 0; i < 8; ++i) pre[i] = *(const f32x4*)(g + 4 * i);
  };
  auto write_chunk = [&]() {
    float ps = 0.f;
#pragma unroll
    for (int i = 0; i < 8; ++i) {
#pragma unroll
      for (int j = 0; j < 4; ++j) {
        float v = pre[i][j];
        int d = sdh + 4 * i + j;
        Bt[d * KB + wj * 64 + wtx * 4 + wi] = v;
        ps += v * v;
      }
    }
    ps += __shfl_xor(ps, 1, 64);    // combine the two d-halves (t and t^1 share se)
    if ((t & 1) == 0) esq_s[se] = ps;
  };

  float minv[MT];
  int mini[MT];
#pragma unroll
  for (int m = 0; m < MT; ++m) { minv[m] = 3.4e38f; mini[m] = 0; }

  load_chunk(0);
  write_chunk();
  __syncthreads();                  // drains A-stage vmcnt + Bt writes

  const int tySwz = (ty & 7) << 4;                 // byte XOR for A reads
  const char* Abase = (const char*)(A + (ty * MT) * D_);
  const char* Bbase = (const char*)(Bt + tx * 4);

  for (int c = 0; c < NCHUNK; ++c) {
    if (c + 1 < NCHUNK) load_chunk(c + 1);         // issue-early (T14)

    float acc[MT][NT];
#pragma unroll
    for (int m = 0; m < MT; ++m)
#pragma unroll
      for (int n = 0; n < NT; ++n) acc[m][n] = 0.f;

#pragma unroll 2
    for (int d0 = 0; d0 < D_; d0 += 4) {
      const char* arow = Abase + ((d0 << 2) ^ tySwz);   // swizzled 16B group
      f32x4 a[MT];
#pragma unroll
      for (int m = 0; m < MT; ++m)
        a[m] = *(const f32x4*)(arow + m * 256);         // query stride = 256 B
#pragma unroll
      for (int dd = 0; dd < 4; ++dd) {
        f32x4 b[4];
        const char* brow = Bbase + (d0 + dd) * 1024;
#pragma unroll
        for (int j = 0; j < 4; ++j)
          b[j] = *(const f32x4*)(brow + j * 256);       // 16B-stride lanes: 2-way = free
#pragma unroll
        for (int m = 0; m < MT; ++m) {
          float av = a[m][dd];
#pragma unroll
          for (int j = 0; j < 4; ++j)
#pragma unroll
            for (int i = 0; i < 4; ++i)
              acc[m][4 * j + i] += av * b[j][i];
        }
      }
    }

    // score = 0.5*||e||^2 - c.e  (same argmin order as ||c-e||^2)
    const int ebase = c * KB + tx * NT;
#pragma unroll
    for (int n = 0; n < NT; ++n) {
      float sc_base = 0.5f * esq_s[tx * NT + n];
#pragma unroll
      for (int m = 0; m < MT; ++m) {
        float sc = sc_base - acc[m][n];
        if (sc < minv[m]) { minv[m] = sc; mini[m] = ebase + n; }  // strict <: first-min wins
      }
    }

    __syncthreads();                // everyone done reading Bt
    if (c + 1 < NCHUNK) {
      write_chunk();                // write-late (vmcnt auto-drained by use)
      __syncthreads();
    }
  }

  // ---- cross-lane argmin across the 16 tx-lanes sharing each query ----
#pragma unroll
  for (int off = 1; off < 16; off <<= 1) {
#pragma unroll
    for (int m = 0; m < MT; ++m) {
      float ov = __shfl_xor(minv[m], off, 64);
      int oi = __shfl_xor(mini[m], off, 64);
      if (ov < minv[m] || (ov == minv[m] && oi < mini[m])) {
        minv[m] = ov; mini[m] = oi;
      }
    }
  }
  if (tx == 0) {
#pragma unroll
    for (int m = 0; m < MT; ++m) best_s[ty * MT + m] = mini[m];
  }
  __syncthreads();

  // ---- gather: out[q][:] = codebook[best[q]][:]  (coalesced float4) ----
#pragma unroll
  for (int i = 0; i < 8; ++i) {
    int f = t + NTHREADS * i;       // float4 index, 4096 per block
    int q = f >> 4;                 // 16 float4 per row
    int c4 = f & 15;
    int e = best_s[q];
    f32x4 v = *(const f32x4*)(codebook + e * D_ + c4 * 4);
    *(f32x4*)(out + (qbase + q) * D_ + c4 * 4) = v;
  }
}

extern "C" void kernel_launch(void* const* d_in, const int* in_sizes, int n_in,
                              void* d_out, int out_size, void* d_ws, size_t ws_size,
                              hipStream_t stream) {
  const float* codes = (const float*)d_in[0];
  const float* codebook = (const float*)d_in[1];
  float* out = (float*)d_out;
  const int Q = in_sizes[0] / D_;   // 65536
  const int grid = Q / QB;          // 256
  vq_assign_gather<<<grid, NTHREADS, 0, stream>>>(codes, codebook, out);
}

// Round 4
// 73.676 us; speedup vs baseline: 1.3267x; 1.3267x over previous
//
#include <hip/hip_runtime.h>

typedef __attribute__((ext_vector_type(4))) float f32x4;

#define D_ 64
#define K_ 512
#define QB 128          // queries per block; grid = 512
#define MT 8            // queries per thread (ty: 16 groups)
#define NT 16           // entries per thread (tx: 32 groups)
#define NTHREADS 512

__device__ __forceinline__ void gload_lds16(const float* g, float* lds) {
  __builtin_amdgcn_global_load_lds(
      (const __attribute__((address_space(1))) void*)g,
      (__attribute__((address_space(3))) void*)lds, 16, 0, 0);
}

// LDS (exactly 160 KB, round-3 confirmed zero padding):
//   A_sh: [q][g]  32 KB, 16B-group g swizzled by key (q>>3)&15
//   B_sh: [e][g] 128 KB, 16B-group g swizzled by key (e>>4)&15
// Both staged with global_load_lds + pre-swizzled per-lane SOURCE (linear dest).
__global__ __launch_bounds__(NTHREADS, 1)   // (512,2) empirically caps VGPR=128 -> spills; (512,1) -> cap 256
void vq_assign_gather(const float* __restrict__ codes,
                      const float* __restrict__ codebook,
                      float* __restrict__ out) {
  __shared__ float A_sh[QB * D_];
  __shared__ float B_sh[K_ * D_];

  const int t = threadIdx.x;
  const int w = t >> 6;                       // wave 0..7
  const int l = t & 63;                       // lane
  // wave = 16 tx-low x 4 ty-low; tx bit4 from wave bit0, ty bits2-3 from wave bits1-2
  const int tx = (t & 15) | (((t >> 6) & 1) << 4);        // 0..31, 16 entries each
  const int ty = ((t >> 4) & 3) | (((t >> 7) & 3) << 2);  // 0..15, 8 queries each
  const long long qbase = (long long)blockIdx.x * QB;

  // ---- stage A (32 KB = 4 gload/wave), source pre-swizzled by (q>>3)&15 ----
  {
    const float* srcA = codes + qbase * D_;
#pragma unroll
    for (int r = 0; r < 4; ++r) {
      const int q = (w * 4 + r) * 4 + (l >> 4);
      const int g = l & 15;
      gload_lds16(srcA + q * 64 + (((g ^ (q >> 3)) & 15) << 2),
                  A_sh + (w * 4 + r) * 256);
    }
  }
  // ---- stage B (128 KB = 16 gload/wave), source pre-swizzled by (e>>4)&15 ----
  {
#pragma unroll
    for (int r = 0; r < 16; ++r) {
      const int e = (w * 16 + r) * 4 + (l >> 4);
      const int g = l & 15;
      gload_lds16(codebook + e * 64 + (((g ^ (e >> 4)) & 15) << 2),
                  B_sh + (w * 16 + r) * 256);
    }
  }
  __syncthreads();    // compiler drains vmcnt before s_barrier

  float acc[MT][NT];
#pragma unroll
  for (int m = 0; m < MT; ++m)
#pragma unroll
    for (int n = 0; n < NT; ++n) acc[m][n] = 0.f;
  float esq[NT];
#pragma unroll
  for (int n = 0; n < NT; ++n) esq[n] = 0.f;

  const char* Abase = (const char*)A_sh + (ty * MT) * 256;  // + m*256 + swz group
  const char* Bbase = (const char*)B_sh + tx * 4096;        // + n*256 + swz group
  const int aSwz = (ty & 15) << 4;
  const int bSwz = (tx & 15) << 4;

#pragma unroll 2
  for (int d0 = 0; d0 < 16; ++d0) {           // 16B dim-groups (4 dims each)
    const char* ag = Abase + ((d0 << 4) ^ aSwz);
    f32x4 a[MT];
#pragma unroll
    for (int m = 0; m < MT; ++m)
      a[m] = *(const f32x4*)(ag + m * 256);   // 4 distinct addrs/wave, swz -> conflict-free
    const char* bg = Bbase + ((d0 << 4) ^ bSwz);
#pragma unroll
    for (int bb = 0; bb < 4; ++bb) {          // entries in batches of 4 (caps live regs)
      f32x4 b[4];
#pragma unroll
      for (int k = 0; k < 4; ++k)
        b[k] = *(const f32x4*)(bg + (bb * 4 + k) * 256);
#pragma unroll
      for (int k = 0; k < 4; ++k) {
        esq[bb * 4 + k] += b[k][0] * b[k][0] + b[k][1] * b[k][1]
                         + b[k][2] * b[k][2] + b[k][3] * b[k][3];
#pragma unroll
        for (int m = 0; m < MT; ++m) {
#pragma unroll
          for (int dd = 0; dd < 4; ++dd)
            acc[m][bb * 4 + k] += a[m][dd] * b[k][dd];
        }
      }
    }
  }

  // ---- per-thread argmin over its 16 entries (ascending n: first-min wins) ----
  float minv[MT];
  int mini[MT];
#pragma unroll
  for (int m = 0; m < MT; ++m) { minv[m] = 3.4e38f; mini[m] = 0; }
#pragma unroll
  for (int n = 0; n < NT; ++n) {
    const float half_esq = 0.5f * esq[n];
    const int e = tx * NT + n;
#pragma unroll
    for (int m = 0; m < MT; ++m) {
      float sc = half_esq - acc[m][n];        // = 0.5||e||^2 - c.e, same order as dist
      if (sc < minv[m]) { minv[m] = sc; mini[m] = e; }
    }
  }
  // ---- reduce across the 16 tx-low lanes in-wave ----
#pragma unroll
  for (int off = 1; off < 16; off <<= 1) {
#pragma unroll
    for (int m = 0; m < MT; ++m) {
      float ov = __shfl_xor(minv[m], off, 64);
      int oi = __shfl_xor(mini[m], off, 64);
      if (ov < minv[m] || (ov == minv[m] && oi < mini[m])) {
        minv[m] = ov; mini[m] = oi;
      }
    }
  }

  // ---- combine the two tx-halves (wave pairs) via scratch overlaid on dead A ----
  __syncthreads();                            // all LDS reads of A done
  float* sc_s = (float*)A_sh;                 // [128][2]
  int* ix_s = (int*)A_sh + 256;               // [128][2]
  int* best = (int*)A_sh + 512;               // [128]
  if ((t & 15) == 0) {
    const int half = (t >> 6) & 1;            // tx-half: entries 0-255 vs 256-511
#pragma unroll
    for (int m = 0; m < MT; ++m) {
      const int q = ty * MT + m;
      sc_s[q * 2 + half] = minv[m];
      ix_s[q * 2 + half] = mini[m];
    }
  }
  __syncthreads();
  if (t < QB) {
    float s0 = sc_s[t * 2], s1 = sc_s[t * 2 + 1];
    int i0 = ix_s[t * 2], i1 = ix_s[t * 2 + 1];
    best[t] = (s1 < s0) ? i1 : i0;            // tie -> i0 (lower index half)
  }
  __syncthreads();

  // ---- gather from LDS-resident codebook (swizzled read) ----
#pragma unroll
  for (int i = 0; i < 4; ++i) {
    const int f = t + NTHREADS * i;           // 2048 f32x4 per block
    const int q = f >> 4;
    const int g = f & 15;
    const int e = best[q];
    f32x4 v = *(const f32x4*)((const char*)B_sh + e * 256 +
                              (((g ^ (e >> 4)) & 15) << 4));
    *(f32x4*)(out + (qbase + q) * D_ + g * 4) = v;
  }
}

extern "C" void kernel_launch(void* const* d_in, const int* in_sizes, int n_in,
                              void* d_out, int out_size, void* d_ws, size_t ws_size,
                              hipStream_t stream) {
  const float* codes = (const float*)d_in[0];
  const float* codebook = (const float*)d_in[1];
  float* out = (float*)d_out;
  const int Q = in_sizes[0] / D_;   // 65536
  const int grid = Q / QB;          // 512
  vq_assign_gather<<<grid, NTHREADS, 0, stream>>>(codes, codebook, out);
}

// Round 5
// 34.607 us; speedup vs baseline: 2.8244x; 2.1289x over previous
//
#include <hip/hip_runtime.h>

typedef __attribute__((ext_vector_type(4))) float f32x4;
typedef __attribute__((ext_vector_type(8))) _Float16 f16x8;
typedef __attribute__((ext_vector_type(4))) _Float16 f16x4;

#define D_ 64
#define K_ 512
#define QC 64      // queries per chunk
#define NCH 4      // chunks per block (256 queries/block, grid 256)
#define NTHREADS 256

// 2-limb f16 trick: a = hi + lo (22 mantissa bits). K-concat limbs (128 halves).
// Pass1 (matched k) = Ah.Bh + Al.Bl ; Pass2 (k offset 64) = Ah.Bl + Al.Bh.
// Frag-blocked LDS: FB(tile,kb,ko,r) halves addr = tile*2048 + kb*512 + ko*128 + r*8
// -> each wave fragment read is a linear 1KB block (conflict-free, no swizzle).
// Any within-K-block permutation of our packing cancels (A and B use same builder).
__global__ __launch_bounds__(NTHREADS, 1)
void vq_mfma(const float* __restrict__ codes,
             const float* __restrict__ codebook,
             float* __restrict__ out) {
  __shared__ _Float16 Bf[K_ * 128];   // 128 KB codebook frags (entries = MFMA M)
  __shared__ _Float16 Af[QC * 128];   // 16 KB  query frags   (queries = MFMA N)
  __shared__ float esqh[K_];          // 0.5*||e||^2 (fp32)
  __shared__ float smin[4][QC];
  __shared__ int   simin[4][QC];
  __shared__ int   best[QC];

  const int t = threadIdx.x;
  const int w = t >> 6;               // wave 0..3
  const int l = t & 63;
  const int lh = l >> 4;              // k-group
  const int ll = l & 15;              // row (entry) / col (query) within tile
  const long long qb = (long long)blockIdx.x * (QC * NCH);

  // ===== stage codebook once: 2 entries per thread, fp32 -> 2x f16 limbs =====
#pragma unroll
  for (int pass = 0; pass < 2; ++pass) {
    const int e = t + pass * 256;
    const float* src = codebook + e * D_;
    _Float16 hi[D_], lo[D_];
    float es = 0.f;
#pragma unroll
    for (int g = 0; g < 16; ++g) {
      f32x4 v = *(const f32x4*)(src + 4 * g);
#pragma unroll
      for (int j = 0; j < 4; ++j) {
        float a = v[j];
        es += a * a;
        _Float16 h = (_Float16)a;
        hi[4 * g + j] = h;
        lo[4 * g + j] = (_Float16)(a - (float)h);
      }
    }
    esqh[e] = 0.5f * es;
    const int tile = e >> 4, r = e & 15;
    _Float16* dst = Bf + tile * 2048 + r * 8;
#pragma unroll
    for (int kb = 0; kb < 4; ++kb)
#pragma unroll
      for (int ko = 0; ko < 4; ++ko) {
        f16x8 wv;
#pragma unroll
        for (int s = 0; s < 8; ++s) {
          int k = kb * 32 + ko * 4 + (s >> 2) * 16 + (s & 3);  // limb-k within 128
          wv[s] = (k < 64) ? hi[k] : lo[k - 64];
        }
        *(f16x8*)(dst + kb * 512 + ko * 128) = wv;
      }
  }

  // ===== A-stage mapping: thread t -> query aq, dim-part dp (16 dims) =====
  const int aq = t & 63;
  const int dp = t >> 6;
  const int aqt = aq >> 4, ar = aq & 15;
  const int kbh = dp >> 1, sh = dp & 1;
  _Float16* adst = Af + aqt * 2048 + ar * 8 + sh * 4;

  // stage chunk 0 A
  {
    const float* src = codes + (qb + aq) * D_ + dp * 16;
    _Float16 hi[16], lo[16];
#pragma unroll
    for (int g = 0; g < 4; ++g) {
      f32x4 v = *(const f32x4*)(src + 4 * g);
#pragma unroll
      for (int j = 0; j < 4; ++j) {
        float a = v[j];
        _Float16 h = (_Float16)a;
        hi[4 * g + j] = h;
        lo[4 * g + j] = (_Float16)(a - (float)h);
      }
    }
#pragma unroll
    for (int ko = 0; ko < 4; ++ko) {
      f16x4 wh, wl;
#pragma unroll
      for (int j = 0; j < 4; ++j) { wh[j] = hi[ko * 4 + j]; wl[j] = lo[ko * 4 + j]; }
      *(f16x4*)(adst + kbh * 512 + ko * 128) = wh;          // hi limb: k = d
      *(f16x4*)(adst + (2 + kbh) * 512 + ko * 128) = wl;    // lo limb: k = 64 + d
    }
  }
  __syncthreads();

  for (int c = 0; c < NCH; ++c) {
    // ===== compute: wave w owns entry-tiles w*8..w*8+7 (M), all 4 q-tiles (N) =====
    f32x4 acc[8][4];
#pragma unroll
    for (int i = 0; i < 8; ++i)
#pragma unroll
      for (int qt = 0; qt < 4; ++qt) acc[i][qt] = (f32x4){0.f, 0.f, 0.f, 0.f};

#pragma unroll
    for (int ks = 0; ks < 2; ++ks) {      // kb pairs (ks, ks+2)
      f16x8 qf[4][2];
#pragma unroll
      for (int qt = 0; qt < 4; ++qt)
#pragma unroll
        for (int p = 0; p < 2; ++p)
          qf[qt][p] = *(const f16x8*)(Af + qt * 2048 + (ks + 2 * p) * 512 + lh * 128 + ll * 8);
#pragma unroll
      for (int h = 0; h < 2; ++h) {
        f16x8 ef[4][2];
#pragma unroll
        for (int i = 0; i < 4; ++i)
#pragma unroll
          for (int p = 0; p < 2; ++p)
            ef[i][p] = *(const f16x8*)(Bf + (w * 8 + h * 4 + i) * 2048 + (ks + 2 * p) * 512 + lh * 128 + ll * 8);
#pragma unroll
        for (int i = 0; i < 4; ++i)
#pragma unroll
          for (int qt = 0; qt < 4; ++qt) {
            f32x4 a = acc[h * 4 + i][qt];
            a = __builtin_amdgcn_mfma_f32_16x16x32_f16(ef[i][0], qf[qt][0], a, 0, 0, 0);
            a = __builtin_amdgcn_mfma_f32_16x16x32_f16(ef[i][1], qf[qt][1], a, 0, 0, 0);
            a = __builtin_amdgcn_mfma_f32_16x16x32_f16(ef[i][0], qf[qt][1], a, 0, 0, 0);
            a = __builtin_amdgcn_mfma_f32_16x16x32_f16(ef[i][1], qf[qt][0], a, 0, 0, 0);
            acc[h * 4 + i][qt] = a;
          }
      }
    }

    // ===== per-lane argmin: lane holds rows (entries) lh*4+r of its 8 tiles =====
    float mv[4]; int mi[4];
#pragma unroll
    for (int qt = 0; qt < 4; ++qt) { mv[qt] = 3.4e38f; mi[qt] = 0; }
#pragma unroll
    for (int i = 0; i < 8; ++i) {
      const int tile = w * 8 + i;
      f32x4 eq = *(const f32x4*)(esqh + tile * 16 + lh * 4);
#pragma unroll
      for (int r = 0; r < 4; ++r) {
        const int e = tile * 16 + lh * 4 + r;     // ascending e: strict < = first-min
#pragma unroll
        for (int qt = 0; qt < 4; ++qt) {
          float sc = eq[r] - acc[i][qt][r];       // 0.5||e||^2 - c.e
          if (sc < mv[qt]) { mv[qt] = sc; mi[qt] = e; }
        }
      }
    }
    // cross-lane: k-groups (lh) hold different entries; col (query) preserved
#pragma unroll
    for (int off = 16; off <= 32; off <<= 1)
#pragma unroll
      for (int qt = 0; qt < 4; ++qt) {
        float ov = __shfl_xor(mv[qt], off, 64);
        int oi = __shfl_xor(mi[qt], off, 64);
        if (ov < mv[qt] || (ov == mv[qt] && oi < mi[qt])) { mv[qt] = ov; mi[qt] = oi; }
      }
    if (l < 16) {
#pragma unroll
      for (int qt = 0; qt < 4; ++qt) {
        smin[w][qt * 16 + l] = mv[qt];
        simin[w][qt * 16 + l] = mi[qt];
      }
    }
    __syncthreads();

    // issue next-chunk A global loads early (hide under combine+gather)
    f32x4 av[4];
    if (c + 1 < NCH) {
      const float* src = codes + (qb + (c + 1) * 64 + aq) * D_ + dp * 16;
#pragma unroll
      for (int g = 0; g < 4; ++g) av[g] = *(const f32x4*)(src + 4 * g);
    }

    if (t < QC) {     // combine 4 waves (disjoint ascending entry ranges)
      float bv = smin[0][t]; int bi = simin[0][t];
#pragma unroll
      for (int wv2 = 1; wv2 < 4; ++wv2) {
        float v = smin[wv2][t]; int ii = simin[wv2][t];
        if (v < bv || (v == bv && ii < bi)) { bv = v; bi = ii; }
      }
      best[t] = bi;
    }
    __syncthreads();

    // epilogue gather: out[q] = codebook[best[q]] (exact fp32 from global, L2-hot)
    {
      const int q = t >> 2, part = t & 3;
      const int e = best[q];
      const f32x4* s4 = (const f32x4*)(codebook + e * D_) + part * 4;
      f32x4* o4 = (f32x4*)(out + (qb + c * 64 + q) * D_) + part * 4;
#pragma unroll
      for (int j = 0; j < 4; ++j) o4[j] = s4[j];
    }

    // write next-chunk A frags (Af reads for chunk c all completed pre-barrier)
    if (c + 1 < NCH) {
      _Float16 hi[16], lo[16];
#pragma unroll
      for (int g = 0; g < 4; ++g)
#pragma unroll
        for (int j = 0; j < 4; ++j) {
          float a = av[g][j];
          _Float16 h = (_Float16)a;
          hi[4 * g + j] = h;
          lo[4 * g + j] = (_Float16)(a - (float)h);
        }
#pragma unroll
      for (int ko = 0; ko < 4; ++ko) {
        f16x4 wh, wl;
#pragma unroll
        for (int j = 0; j < 4; ++j) { wh[j] = hi[ko * 4 + j]; wl[j] = lo[ko * 4 + j]; }
        *(f16x4*)(adst + kbh * 512 + ko * 128) = wh;
        *(f16x4*)(adst + (2 + kbh) * 512 + ko * 128) = wl;
      }
      __syncthreads();   // uniform branch: safe
    }
  }
}

extern "C" void kernel_launch(void* const* d_in, const int* in_sizes, int n_in,
                              void* d_out, int out_size, void* d_ws, size_t ws_size,
                              hipStream_t stream) {
  const float* codes = (const float*)d_in[0];
  const float* codebook = (const float*)d_in[1];
  float* out = (float*)d_out;
  const int Q = in_sizes[0] / D_;        // 65536
  const int grid = Q / (QC * NCH);       // 256
  vq_mfma<<<grid, NTHREADS, 0, stream>>>(codes, codebook, out);
}

// Round 6
// 30.782 us; speedup vs baseline: 3.1754x; 1.1243x over previous
//
#include <hip/hip_runtime.h>

typedef __attribute__((ext_vector_type(4))) float f32x4;
typedef __attribute__((ext_vector_type(8))) _Float16 f16x8;
typedef __attribute__((ext_vector_type(4))) _Float16 f16x4;

#define D_ 64
#define K_ 512

// 2-limb f16: a = hi + lo (22 mantissa bits). Limbs K-concatenated (128 k's):
// k = d for hi, 64+d for lo. Frag-blocked layout (identical builder everywhere,
// so any within-K-block permutation cancels in A.B):
//   halves offset = tile*2048 + kb*512 + ko*128 + r*8 + s,  k = kb*32+ko*4+(s>>2)*16+(s&3)
// Pass1 (matched kb): Bh.Ah (kb0,1) + Bl.Al (kb2,3). Pass2 (cross): kb2.kb0 etc.

// ===================== prep: codebook -> ws frags + 0.5||e||^2 =====================
__global__ __launch_bounds__(128, 1)
void vq_prep(const float* __restrict__ cb, _Float16* __restrict__ bf,
             float* __restrict__ esq) {
  const int tid = blockIdx.x * 128 + threadIdx.x;   // grid 8 x 128 = 1024
  const int e = tid >> 1, half = tid & 1;           // 2 threads per entry
  const float* src = cb + e * D_ + half * 32;
  _Float16 hi[32], lo[32];
  float es = 0.f;
#pragma unroll
  for (int g = 0; g < 8; ++g) {
    f32x4 v = *(const f32x4*)(src + 4 * g);
#pragma unroll
    for (int j = 0; j < 4; ++j) {
      float a = v[j];
      es += a * a;
      _Float16 h = (_Float16)a;
      hi[4 * g + j] = h;
      lo[4 * g + j] = (_Float16)(a - (float)h);
    }
  }
  es += __shfl_xor(es, 1, 64);                      // combine the two halves
  if (half == 0) esq[e] = 0.5f * es;
  const int tile = e >> 4, r = e & 15;
  _Float16* dst = bf + tile * 2048 + r * 8;
#pragma unroll
  for (int ko = 0; ko < 4; ++ko) {
    f16x8 wh, wl;
#pragma unroll
    for (int s = 0; s < 8; ++s) {
      int loc = ko * 4 + (s >> 2) * 16 + (s & 3);   // local k within 32-block
      wh[s] = hi[loc];
      wl[s] = lo[loc];
    }
    *(f16x8*)(dst + half * 512 + ko * 128) = wh;        // kb = half     (k = d)
    *(f16x8*)(dst + (2 + half) * 512 + ko * 128) = wl;  // kb = 2+half   (k = 64+d)
  }
}

// ===================== main: 256 blocks x 512 thr, Q=256/block =====================
__global__ __launch_bounds__(512, 1)
void vq_main(const float* __restrict__ codes, const float* __restrict__ codebook,
             const _Float16* __restrict__ bf, const float* __restrict__ esq,
             float* __restrict__ out) {
  __shared__ _Float16 Af[2][64 * 128];   // 32 KB (double-buffered query frags)
  __shared__ float smin[8][256];         // 8 KB
  __shared__ int   simin[8][256];        // 8 KB
  __shared__ int   best[256];            // 1 KB

  const int t = threadIdx.x;
  const int w = t >> 6, l = t & 63, lh = l >> 4, ll = l & 15;
  const long long qb = (long long)blockIdx.x * 256;

  // ---- B frags + esq into registers, once per block (L2-hot after 1st block/XCD) ----
  f16x8 ef[4][4];                        // [tile][kb], wave owns tiles w*4..w*4+3
  f32x4 esqr[4];
#pragma unroll
  for (int i = 0; i < 4; ++i) {
#pragma unroll
    for (int kb = 0; kb < 4; ++kb)
      ef[i][kb] = *(const f16x8*)(bf + (w * 4 + i) * 2048 + kb * 512 + l * 8);
    esqr[i] = *(const f32x4*)(esq + (w * 4 + i) * 16 + lh * 4);
  }

  // ---- A staging: thread -> query aq (0..63), dim-part dpart (8 dims) ----
  const int aq = t >> 3, dpart = t & 7;
  const int kbh = dpart >> 2, hi16 = (dpart >> 1) & 1, ko0 = (dpart & 1) * 2;
  _Float16* adst0 = &Af[0][(aq >> 4) * 2048 + (aq & 15) * 8 + hi16 * 4];
  const int bufStride = 64 * 128;

  auto stage_write = [&](int buf, const f32x4* av) {
    _Float16 hi[8], lo[8];
#pragma unroll
    for (int g = 0; g < 2; ++g)
#pragma unroll
      for (int j = 0; j < 4; ++j) {
        float a = av[g][j];
        _Float16 h = (_Float16)a;
        hi[4 * g + j] = h;
        lo[4 * g + j] = (_Float16)(a - (float)h);
      }
    _Float16* ad = adst0 + buf * bufStride;
#pragma unroll
    for (int p = 0; p < 2; ++p) {
      f16x4 wh, wl;
#pragma unroll
      for (int j = 0; j < 4; ++j) { wh[j] = hi[p * 4 + j]; wl[j] = lo[p * 4 + j]; }
      *(f16x4*)(ad + kbh * 512 + (ko0 + p) * 128) = wh;        // hi: k = d
      *(f16x4*)(ad + (2 + kbh) * 512 + (ko0 + p) * 128) = wl;  // lo: k = 64+d
    }
  };

  // stage chunk 0 (coalesced: 8 lanes cover one query's 64 dims)
  {
    const float* src = codes + (qb + aq) * D_ + dpart * 8;
    f32x4 av[2] = { *(const f32x4*)src, *(const f32x4*)(src + 4) };
    stage_write(0, av);
  }
  __syncthreads();

  int cur = 0;
  for (int c = 0; c < 4; ++c) {
    // issue next chunk's global loads early (hide HBM latency under MFMA)
    f32x4 av[2];
    if (c < 3) {
      const float* src = codes + (qb + (c + 1) * 64 + aq) * D_ + dpart * 8;
      av[0] = *(const f32x4*)src;
      av[1] = *(const f32x4*)(src + 4);
    }

    f32x4 acc[4][4];
#pragma unroll
    for (int i = 0; i < 4; ++i)
#pragma unroll
      for (int qt = 0; qt < 4; ++qt) acc[i][qt] = (f32x4){0.f, 0.f, 0.f, 0.f};

#pragma unroll
    for (int qt = 0; qt < 4; ++qt) {
      f16x8 qf[4];
#pragma unroll
      for (int kb = 0; kb < 4; ++kb)
        qf[kb] = *(const f16x8*)(&Af[0][cur * bufStride + qt * 2048 + kb * 512 + l * 8]);
#pragma unroll
      for (int i = 0; i < 4; ++i) {
        f32x4 a = acc[i][qt];
        a = __builtin_amdgcn_mfma_f32_16x16x32_f16(ef[i][0], qf[0], a, 0, 0, 0);  // Bh.Ah
        a = __builtin_amdgcn_mfma_f32_16x16x32_f16(ef[i][1], qf[1], a, 0, 0, 0);
        a = __builtin_amdgcn_mfma_f32_16x16x32_f16(ef[i][2], qf[2], a, 0, 0, 0);  // Bl.Al
        a = __builtin_amdgcn_mfma_f32_16x16x32_f16(ef[i][3], qf[3], a, 0, 0, 0);
        a = __builtin_amdgcn_mfma_f32_16x16x32_f16(ef[i][2], qf[0], a, 0, 0, 0);  // Bl.Ah
        a = __builtin_amdgcn_mfma_f32_16x16x32_f16(ef[i][3], qf[1], a, 0, 0, 0);
        a = __builtin_amdgcn_mfma_f32_16x16x32_f16(ef[i][0], qf[2], a, 0, 0, 0);  // Bh.Al
        a = __builtin_amdgcn_mfma_f32_16x16x32_f16(ef[i][1], qf[3], a, 0, 0, 0);
        acc[i][qt] = a;
      }
    }

    // per-lane argmin; lane holds query col = ll, entries (w*4+i)*16 + lh*4 + r
    float mv[4]; int mi[4];
#pragma unroll
    for (int qt = 0; qt < 4; ++qt) { mv[qt] = 3.4e38f; mi[qt] = 0; }
#pragma unroll
    for (int i = 0; i < 4; ++i)
#pragma unroll
      for (int r = 0; r < 4; ++r) {
        const int e = (w * 4 + i) * 16 + lh * 4 + r;   // ascending: strict < = first-min
        const float eq = esqr[i][r];
#pragma unroll
        for (int qt = 0; qt < 4; ++qt) {
          float sc = eq - acc[i][qt][r];               // 0.5||e||^2 - c.e
          if (sc < mv[qt]) { mv[qt] = sc; mi[qt] = e; }
        }
      }
    // reduce across the 4 lh groups (same query col, different entries)
#pragma unroll
    for (int off = 16; off <= 32; off <<= 1)
#pragma unroll
      for (int qt = 0; qt < 4; ++qt) {
        float ov = __shfl_xor(mv[qt], off, 64);
        int oi = __shfl_xor(mi[qt], off, 64);
        if (ov < mv[qt] || (ov == mv[qt] && oi < mi[qt])) { mv[qt] = ov; mi[qt] = oi; }
      }
    if (l < 16) {
#pragma unroll
      for (int qt = 0; qt < 4; ++qt) {
        smin[w][c * 64 + qt * 16 + ll] = mv[qt];
        simin[w][c * 64 + qt * 16 + ll] = mi[qt];
      }
    }

    if (c < 3) stage_write(cur ^ 1, av);   // write-late into the other buffer
    __syncthreads();                       // Af[cur^1] ready; smin visible at end
    cur ^= 1;
  }

  // ---- combine 8 waves (disjoint ascending entry ranges; tie -> lower index) ----
  if (t < 256) {
    float bv = smin[0][t]; int bi = simin[0][t];
#pragma unroll
    for (int ww = 1; ww < 8; ++ww) {
      float v = smin[ww][t]; int ii = simin[ww][t];
      if (v < bv || (v == bv && ii < bi)) { bv = v; bi = ii; }
    }
    best[t] = bi;
  }
  __syncthreads();

  // ---- gather: exact fp32 rows from global codebook (L2-hot) ----
#pragma unroll
  for (int i2 = 0; i2 < 8; ++i2) {
    const int f = t + 512 * i2;            // 4096 f32x4 per block
    const int q = f >> 4, g = f & 15;
    const int e = best[q];
    f32x4 v = *(const f32x4*)(codebook + e * D_ + g * 4);
    *(f32x4*)(out + (qb + q) * D_ + g * 4) = v;
  }
}

extern "C" void kernel_launch(void* const* d_in, const int* in_sizes, int n_in,
                              void* d_out, int out_size, void* d_ws, size_t ws_size,
                              hipStream_t stream) {
  const float* codes = (const float*)d_in[0];
  const float* codebook = (const float*)d_in[1];
  float* out = (float*)d_out;
  _Float16* bf = (_Float16*)d_ws;                        // 128 KB frag image
  float* esq = (float*)((char*)d_ws + 131072);           // 2 KB norms
  vq_prep<<<8, 128, 0, stream>>>(codebook, bf, esq);
  vq_main<<<256, 512, 0, stream>>>(codes, codebook, bf, esq, out);
}

// Round 7
// 30.604 us; speedup vs baseline: 3.1939x; 1.0058x over previous
//
#include <hip/hip_runtime.h>

typedef __attribute__((ext_vector_type(4))) float f32x4;
typedef __attribute__((ext_vector_type(8))) _Float16 f16x8;
typedef __attribute__((ext_vector_type(4))) _Float16 f16x4;

#define D_ 64
#define K_ 512

// 2-limb f16: a = hi + lo (22 mantissa bits). Limbs K-concatenated (128 k's):
// k = d for hi, 64+d for lo. Frag-blocked layout (identical builder for A and B,
// so any within-K-block permutation cancels in A.B):
//   halves offset = tile*2048 + kb*512 + ko*128 + r*8 + s, k = kb*32+ko*4+(s>>2)*16+(s&3)
// Score = 0.5||e||^2 - c.e using Bh.Ah + Bl.Ah + Bh.Al (lo.lo dropped: ~4e-6 error).

// ===================== prep: codebook -> ws frags + 0.5||e||^2 =====================
__global__ __launch_bounds__(128, 1)
void vq_prep(const float* __restrict__ cb, _Float16* __restrict__ bf,
             float* __restrict__ esq) {
  const int tid = blockIdx.x * 128 + threadIdx.x;   // grid 8 x 128 = 1024
  const int e = tid >> 1, half = tid & 1;           // 2 threads per entry
  const float* src = cb + e * D_ + half * 32;
  _Float16 hi[32], lo[32];
  float es = 0.f;
#pragma unroll
  for (int g = 0; g < 8; ++g) {
    f32x4 v = *(const f32x4*)(src + 4 * g);
#pragma unroll
    for (int j = 0; j < 4; ++j) {
      float a = v[j];
      es += a * a;
      _Float16 h = (_Float16)a;
      hi[4 * g + j] = h;
      lo[4 * g + j] = (_Float16)(a - (float)h);
    }
  }
  es += __shfl_xor(es, 1, 64);                      // combine the two halves
  if (half == 0) esq[e] = 0.5f * es;
  const int tile = e >> 4, r = e & 15;
  _Float16* dst = bf + tile * 2048 + r * 8;
#pragma unroll
  for (int ko = 0; ko < 4; ++ko) {
    f16x8 wh, wl;
#pragma unroll
    for (int s = 0; s < 8; ++s) {
      int loc = ko * 4 + (s >> 2) * 16 + (s & 3);   // local k within 32-block
      wh[s] = hi[loc];
      wl[s] = lo[loc];
    }
    *(f16x8*)(dst + half * 512 + ko * 128) = wh;        // kb = half     (k = d)
    *(f16x8*)(dst + (2 + half) * 512 + ko * 128) = wl;  // kb = 2+half   (k = 64+d)
  }
}

// ============ main: 256 blocks x 1024 thr (16 waves, 4/SIMD), Q=256/block ============
__global__ __launch_bounds__(1024, 4)
void vq_main(const float* __restrict__ codes, const float* __restrict__ codebook,
             const _Float16* __restrict__ bf, const float* __restrict__ esq,
             float* __restrict__ out) {
  __shared__ _Float16 Af[2][64 * 128];   // 32 KB (double-buffered query frags)
  __shared__ float smin[16][256];        // 16 KB
  __shared__ int   simin[16][256];       // 16 KB
  __shared__ int   best[256];            // 1 KB

  const int t = threadIdx.x;
  const int w = t >> 6, l = t & 63, lh = l >> 4, ll = l & 15;
  const long long qb = (long long)blockIdx.x * 256;

  // ---- B frags + esq into registers (wave owns tiles 2w, 2w+1; L2-hot ws) ----
  f16x8 ef[2][4];
  f32x4 esqr[2];
#pragma unroll
  for (int i = 0; i < 2; ++i) {
#pragma unroll
    for (int kb = 0; kb < 4; ++kb)
      ef[i][kb] = *(const f16x8*)(bf + (w * 2 + i) * 2048 + kb * 512 + l * 8);
    esqr[i] = *(const f32x4*)(esq + (w * 2 + i) * 16 + lh * 4);
  }

  // ---- A staging: thread -> query aq (0..63), 4 dims at d0 = (t&15)*4 ----
  const int aq = t >> 4, dpart = t & 15;
  const int d0 = dpart * 4;
  const int kbA = d0 >> 5;                  // 0 or 1
  const int x0 = d0 & 31;
  const int koA = (x0 >> 2) & 3;
  const int sh4 = ((x0 >> 4) & 1) * 4;      // s-slot half within the 8-group
  _Float16* adst0 = &Af[0][(aq >> 4) * 2048 + (aq & 15) * 8 + sh4];
  const int bufStride = 64 * 128;

  auto stage_write = [&](int buf, f32x4 av) {
    f16x4 wh, wl;
#pragma unroll
    for (int j = 0; j < 4; ++j) {
      float a = av[j];
      _Float16 h = (_Float16)a;
      wh[j] = h;
      wl[j] = (_Float16)(a - (float)h);
    }
    _Float16* ad = adst0 + buf * bufStride;
    *(f16x4*)(ad + kbA * 512 + koA * 128) = wh;          // hi: k = d
    *(f16x4*)(ad + (2 + kbA) * 512 + koA * 128) = wl;    // lo: k = 64+d
  };

  // stage chunk 0 (coalesced: 16 lanes cover one query's 64 dims)
  stage_write(0, *(const f32x4*)(codes + (qb + aq) * D_ + d0));
  __syncthreads();

  int cur = 0;
  for (int c = 0; c < 4; ++c) {
    // issue next chunk's global load early (hide HBM latency under MFMA)
    f32x4 av;
    if (c < 3) av = *(const f32x4*)(codes + (qb + (c + 1) * 64 + aq) * D_ + d0);

    float mv[4]; int mi[4];
#pragma unroll
    for (int qt = 0; qt < 4; ++qt) { mv[qt] = 3.4e38f; mi[qt] = 0; }

#pragma unroll
    for (int qt = 0; qt < 4; ++qt) {
      f16x8 qf[4];
#pragma unroll
      for (int kb = 0; kb < 4; ++kb)
        qf[kb] = *(const f16x8*)(&Af[0][cur * bufStride + qt * 2048 + kb * 512 + l * 8]);
#pragma unroll
      for (int i = 0; i < 2; ++i) {
        f32x4 a = (f32x4){0.f, 0.f, 0.f, 0.f};
        a = __builtin_amdgcn_mfma_f32_16x16x32_f16(ef[i][0], qf[0], a, 0, 0, 0); // Bh.Ah
        a = __builtin_amdgcn_mfma_f32_16x16x32_f16(ef[i][1], qf[1], a, 0, 0, 0);
        a = __builtin_amdgcn_mfma_f32_16x16x32_f16(ef[i][2], qf[0], a, 0, 0, 0); // Bl.Ah
        a = __builtin_amdgcn_mfma_f32_16x16x32_f16(ef[i][3], qf[1], a, 0, 0, 0);
        a = __builtin_amdgcn_mfma_f32_16x16x32_f16(ef[i][0], qf[2], a, 0, 0, 0); // Bh.Al
        a = __builtin_amdgcn_mfma_f32_16x16x32_f16(ef[i][1], qf[3], a, 0, 0, 0);
        // per-lane argmin fold: lane = query col ll, entries (w*2+i)*16 + lh*4 + r
#pragma unroll
        for (int r = 0; r < 4; ++r) {
          const int e = (w * 2 + i) * 16 + lh * 4 + r;  // ascending: first-min wins
          float sc = esqr[i][r] - a[r];                 // 0.5||e||^2 - c.e
          if (sc < mv[qt]) { mv[qt] = sc; mi[qt] = e; }
        }
      }
    }

    // reduce across the 4 lh groups (same query col, different entries)
#pragma unroll
    for (int off = 16; off <= 32; off <<= 1)
#pragma unroll
      for (int qt = 0; qt < 4; ++qt) {
        float ov = __shfl_xor(mv[qt], off, 64);
        int oi = __shfl_xor(mi[qt], off, 64);
        if (ov < mv[qt] || (ov == mv[qt] && oi < mi[qt])) { mv[qt] = ov; mi[qt] = oi; }
      }
    if (l < 16) {
#pragma unroll
      for (int qt = 0; qt < 4; ++qt) {
        smin[w][c * 64 + qt * 16 + ll] = mv[qt];
        simin[w][c * 64 + qt * 16 + ll] = mi[qt];
      }
    }

    if (c < 3) stage_write(cur ^ 1, av);   // write-late into the other buffer
    __syncthreads();                       // Af[cur^1] ready; smin visible at end
    cur ^= 1;
  }

  // ---- combine 16 waves (disjoint ascending entry ranges; tie -> lower index) ----
  if (t < 256) {
    float bv = smin[0][t]; int bi = simin[0][t];
#pragma unroll
    for (int ww = 1; ww < 16; ++ww) {
      float v = smin[ww][t]; int ii = simin[ww][t];
      if (v < bv || (v == bv && ii < bi)) { bv = v; bi = ii; }
    }
    best[t] = bi;
  }
  __syncthreads();

  // ---- gather: exact fp32 rows from global codebook (L2-hot) ----
#pragma unroll
  for (int i2 = 0; i2 < 4; ++i2) {
    const int f = t + 1024 * i2;           // 4096 f32x4 per block
    const int q = f >> 4, g = f & 15;
    const int e = best[q];
    f32x4 v = *(const f32x4*)(codebook + e * D_ + g * 4);
    *(f32x4*)(out + (qb + q) * D_ + g * 4) = v;
  }
}

extern "C" void kernel_launch(void* const* d_in, const int* in_sizes, int n_in,
                              void* d_out, int out_size, void* d_ws, size_t ws_size,
                              hipStream_t stream) {
  const float* codes = (const float*)d_in[0];
  const float* codebook = (const float*)d_in[1];
  float* out = (float*)d_out;
  _Float16* bf = (_Float16*)d_ws;                        // 128 KB frag image
  float* esq = (float*)((char*)d_ws + 131072);           // 2 KB norms
  vq_prep<<<8, 128, 0, stream>>>(codebook, bf, esq);
  vq_main<<<256, 1024, 0, stream>>>(codes, codebook, bf, esq, out);
}

// Round 8
// 25.352 us; speedup vs baseline: 3.8555x; 1.2072x over previous
//
#include <hip/hip_runtime.h>

typedef __attribute__((ext_vector_type(4))) float f32x4;
typedef __attribute__((ext_vector_type(8))) _Float16 f16x8;
typedef __attribute__((ext_vector_type(4))) _Float16 f16x4;

#define D_ 64
#define K_ 512

// 2-limb f16: a = hi + lo (22 mantissa bits), limbs K-concatenated (128 k's).
// Frag layout (identical builder for A and B => within-K-block permutation cancels):
//   halves off = tile*2048 + kb*512 + ko*128 + r*8 + s, k = kb*32+ko*4+(s>>2)*16+(s&3)
// Query limbs NEGATED at staging; acc seeded with 0.5||e||^2 via MFMA C-operand:
//   score = 0.5||e||^2 - c.e  (lo.lo product dropped, ~1.5e-5 error).
// Wave w owns e-tiles 4w..4w+3 (entries 64w..64w+63) in registers; queries stream
// through LDS in 4 chunks of 64 (double-buffered). 16 ds_read_b128 feed 96 MFMA.
__global__ __launch_bounds__(512, 2)
void vq_fused(const float* __restrict__ codes,
              const float* __restrict__ codebook,
              float* __restrict__ out) {
  __shared__ _Float16 Af[2][64 * 128];   // 32 KB double-buffered query frags
  __shared__ float smin[8][256];         // 8 KB
  __shared__ int   simin[8][256];        // 8 KB
  __shared__ int   best[256];            // 1 KB

  const int t = threadIdx.x;
  const int w = t >> 6, l = t & 63, lh = l >> 4, ll = l & 15;
  const long long qb = (long long)blockIdx.x * 256;

  // ---- chunk-0 A loads issued first (HBM latency hides under ef build) ----
  const int aq = t >> 3, dpart = t & 7, d0 = dpart * 8;
  const float* asrc = codes + (qb + aq) * D_ + d0;
  f32x4 av0 = *(const f32x4*)asrc;
  f32x4 av1 = *(const f32x4*)(asrc + 4);

  // ---- build ef frags + 0.5||e||^2 in-register (once per block) ----
  // lane covers entry e = tile*16+ll, dims lh*4 + 16j + {0..3}, j=0..3
  f16x8 ef[4][4];
  f32x4 esqr[4];
#pragma unroll
  for (int i = 0; i < 4; ++i) {
    const int e = (w * 4 + i) * 16 + ll;
    const float* src = codebook + e * D_ + lh * 4;
    _Float16 hi[4][4], lo[4][4];
    float es = 0.f;
#pragma unroll
    for (int j = 0; j < 4; ++j) {
      f32x4 v = *(const f32x4*)(src + 16 * j);
#pragma unroll
      for (int si = 0; si < 4; ++si) {
        float a = v[si];
        es += a * a;
        _Float16 h = (_Float16)a;
        hi[j][si] = h;
        lo[j][si] = (_Float16)(a - (float)h);
      }
    }
    es += __shfl_xor(es, 16, 64);         // sum the 4 lh groups
    es += __shfl_xor(es, 32, 64);
#pragma unroll
    for (int r = 0; r < 4; ++r)
      esqr[i][r] = 0.5f * __shfl(es, lh * 4 + r, 64);   // entry tile*16+lh*4+r
#pragma unroll
    for (int s = 0; s < 8; ++s) {
      ef[i][0][s] = hi[s >> 2][s & 3];          // k = d            (d = lh*4+16(s>>2)+(s&3))
      ef[i][1][s] = hi[2 + (s >> 2)][s & 3];    // k = 32 + d'
      ef[i][2][s] = lo[s >> 2][s & 3];          // k = 64 + d
      ef[i][3][s] = lo[2 + (s >> 2)][s & 3];    // k = 96 + d'
    }
  }

  // ---- A staging: thread -> query aq, dims d0..d0+7 (negated limbs) ----
  const int bufStride = 64 * 128;
  _Float16* adstq = &Af[0][(aq >> 4) * 2048 + (aq & 15) * 8];

  auto stage_write = [&](int buf, f32x4 v0, f32x4 v1) {
#pragma unroll
    for (int p = 0; p < 2; ++p) {
      const int d = d0 + 4 * p;
      const int kb = d >> 5, ko = (d >> 2) & 3, j16 = (d >> 4) & 1;
      f16x4 wh, wl;
      f32x4 vv = p ? v1 : v0;
#pragma unroll
      for (int si = 0; si < 4; ++si) {
        float na = -vv[si];                       // negate query
        _Float16 h = (_Float16)na;
        wh[si] = h;
        wl[si] = (_Float16)(na - (float)h);
      }
      _Float16* ad = adstq + buf * bufStride + ko * 128 + j16 * 4;
      *(f16x4*)(ad + kb * 512) = wh;              // hi: k = d
      *(f16x4*)(ad + (2 + kb) * 512) = wl;        // lo: k = 64+d
    }
  };

  stage_write(0, av0, av1);
  __syncthreads();

  int cur = 0;
  for (int c = 0; c < 4; ++c) {
    f32x4 nv0, nv1;
    if (c < 3) {                                  // issue-early next chunk
      const float* src = codes + (qb + (c + 1) * 64 + aq) * D_ + d0;
      nv0 = *(const f32x4*)src;
      nv1 = *(const f32x4*)(src + 4);
    }

    float mv[4]; int mi[4];
#pragma unroll
    for (int qt = 0; qt < 4; ++qt) {
      f16x8 qf[4];
#pragma unroll
      for (int kb = 0; kb < 4; ++kb)
        qf[kb] = *(const f16x8*)(&Af[0][cur * bufStride + qt * 2048 + kb * 512 + l * 8]);
      mv[qt] = 3.4e38f; mi[qt] = 0;
#pragma unroll
      for (int i = 0; i < 4; ++i) {
        f32x4 a = esqr[i];                        // C-operand seed: 0.5||e||^2
        a = __builtin_amdgcn_mfma_f32_16x16x32_f16(ef[i][0], qf[0], a, 0, 0, 0); // eh.(-ch)
        a = __builtin_amdgcn_mfma_f32_16x16x32_f16(ef[i][1], qf[1], a, 0, 0, 0);
        a = __builtin_amdgcn_mfma_f32_16x16x32_f16(ef[i][2], qf[0], a, 0, 0, 0); // el.(-ch)
        a = __builtin_amdgcn_mfma_f32_16x16x32_f16(ef[i][3], qf[1], a, 0, 0, 0);
        a = __builtin_amdgcn_mfma_f32_16x16x32_f16(ef[i][0], qf[2], a, 0, 0, 0); // eh.(-cl)
        a = __builtin_amdgcn_mfma_f32_16x16x32_f16(ef[i][1], qf[3], a, 0, 0, 0);
#pragma unroll
        for (int r = 0; r < 4; ++r) {
          const int e = (w * 4 + i) * 16 + lh * 4 + r;  // ascending: first-min wins
          if (a[r] < mv[qt]) { mv[qt] = a[r]; mi[qt] = e; }
        }
      }
      // reduce over the 4 lh groups (same query col, different entries)
#pragma unroll
      for (int off = 16; off <= 32; off <<= 1) {
        float ov = __shfl_xor(mv[qt], off, 64);
        int oi = __shfl_xor(mi[qt], off, 64);
        if (ov < mv[qt] || (ov == mv[qt] && oi < mi[qt])) { mv[qt] = ov; mi[qt] = oi; }
      }
    }
    if (l < 16) {
#pragma unroll
      for (int qt = 0; qt < 4; ++qt) {
        smin[w][c * 64 + qt * 16 + ll] = mv[qt];
        simin[w][c * 64 + qt * 16 + ll] = mi[qt];
      }
    }

    if (c < 3) stage_write(cur ^ 1, nv0, nv1);    // write-late, other buffer
    __syncthreads();
    cur ^= 1;
  }

  // ---- combine 8 waves (disjoint ascending entry ranges; tie -> lower index) ----
  if (t < 256) {
    float bv = smin[0][t]; int bi = simin[0][t];
#pragma unroll
    for (int ww = 1; ww < 8; ++ww) {
      float v = smin[ww][t]; int ii = simin[ww][t];
      if (v < bv || (v == bv && ii < bi)) { bv = v; bi = ii; }
    }
    best[t] = bi;
  }
  __syncthreads();

  // ---- gather: exact fp32 rows from global codebook (L2-hot) ----
#pragma unroll
  for (int i2 = 0; i2 < 8; ++i2) {
    const int f = t + 512 * i2;                   // 4096 f32x4 per block
    const int q = f >> 4, g = f & 15;
    const int e = best[q];
    f32x4 v = *(const f32x4*)(codebook + e * D_ + g * 4);
    *(f32x4*)(out + (qb + q) * D_ + g * 4) = v;
  }
}

extern "C" void kernel_launch(void* const* d_in, const int* in_sizes, int n_in,
                              void* d_out, int out_size, void* d_ws, size_t ws_size,
                              hipStream_t stream) {
  const float* codes = (const float*)d_in[0];
  const float* codebook = (const float*)d_in[1];
  float* out = (float*)d_out;
  const int Q = in_sizes[0] / D_;        // 65536
  const int grid = Q / 256;              // 256
  vq_fused<<<grid, 512, 0, stream>>>(codes, codebook, out);
}